// Round 3
// baseline (662.083 us; speedup 1.0000x reference)
//
#include <hip/hip_runtime.h>
#include <hip/hip_bf16.h>
#include <stdint.h>

typedef __bf16 bf16;
typedef __bf16 bf16x4 __attribute__((ext_vector_type(4)));
typedef __bf16 bf16x8 __attribute__((ext_vector_type(8)));
typedef float f32x4 __attribute__((ext_vector_type(4)));

#define AS1 __attribute__((address_space(1)))
#define AS3 __attribute__((address_space(3)))

static __device__ __forceinline__ float b2f(bf16 x) { return (float)x; }

static __device__ __forceinline__ void async_cp16(const bf16* g, bf16* l) {
    // width=16 global->LDS DMA; LDS dest is wave-uniform base + lane*16
    __builtin_amdgcn_global_load_lds((const AS1 void*)g, (AS3 void*)l, 16, 0, 0);
}

static __device__ __forceinline__ bf16x4 cvt4(f32x4 v) {
    bf16x4 r;
    r[0] = (bf16)v[0]; r[1] = (bf16)v[1]; r[2] = (bf16)v[2]; r[3] = (bf16)v[3];
    return r;
}

// ---------------------------------------------------------------------------
// Kernel 1: QKV projection. A=[6272,1024] hs fp32, W=[3072,1024] fp32 (B^T).
// 128x128 block tile, BK=32. fp32 tiles are converted to bf16 at LDS-stage
// time so the hot fragment path stays identical to the m97 structure.
// Epilogue scatters Q,K -> [g][pix][64] bf16 and V -> [g][d][pix] bf16.
__global__ __launch_bounds__(256) void qkv_gemm(
    const float* __restrict__ A, const float* __restrict__ W,
    const float* __restrict__ bias, bf16* __restrict__ Qb,
    bf16* __restrict__ Kb, bf16* __restrict__ Vt) {
    __shared__ bf16 As[128 * 32];
    __shared__ bf16 Bs[128 * 32];
    const int t = threadIdx.x;
    const int wid = t >> 6, lane = t & 63;
    const int m0 = blockIdx.x * 128, n0 = blockIdx.y * 128;
    const int wm = (wid & 1) * 64, wn = (wid >> 1) * 64;
    const int lm = lane & 15, quad = lane >> 4;

    f32x4 acc[4][4] = {};
    for (int k0 = 0; k0 < 1024; k0 += 32) {
        __syncthreads();
        for (int i = 0; i < 4; i++) {
            const int idx = t + i * 256;            // 0..1023
            const int row = idx >> 3, c4 = (idx & 7) * 4;
            const f32x4 av = *(const f32x4*)&A[(size_t)(m0 + row) * 1024 + k0 + c4];
            const f32x4 wv = *(const f32x4*)&W[(size_t)(n0 + row) * 1024 + k0 + c4];
            *(bf16x4*)&As[row * 32 + c4] = cvt4(av);
            *(bf16x4*)&Bs[row * 32 + c4] = cvt4(wv);
        }
        __syncthreads();
        bf16x8 af[4], bfr[4];
        for (int x = 0; x < 4; x++) {
            af[x]  = *(const bf16x8*)&As[(wm + x * 16 + lm) * 32 + quad * 8];
            bfr[x] = *(const bf16x8*)&Bs[(wn + x * 16 + lm) * 32 + quad * 8];
        }
        for (int mt = 0; mt < 4; mt++)
            for (int nt = 0; nt < 4; nt++)
                acc[mt][nt] = __builtin_amdgcn_mfma_f32_16x16x32_bf16(af[mt], bfr[nt], acc[mt][nt], 0, 0, 0);
    }
    // epilogue: n = s*1024 + h*64 + d; m = b*1568 + pix
    for (int nt = 0; nt < 4; nt++) {
        const int n_ = n0 + wn + nt * 16 + lm;
        const float bv = bias[n_];
        const int s = n_ >> 10, rem = n_ & 1023;
        const int h = rem >> 6, d = rem & 63;
        for (int mt = 0; mt < 4; mt++) {
            for (int r = 0; r < 4; r++) {
                const int m_ = m0 + wm + mt * 16 + quad * 4 + r;
                const int b = m_ / 1568;
                const int pix = m_ - b * 1568;
                const int g = b * 16 + h;
                const bf16 v = (bf16)(acc[mt][nt][r] + bv);
                if (s == 0)      Qb[((size_t)g * 1568 + pix) * 64 + d] = v;
                else if (s == 1) Kb[((size_t)g * 1568 + pix) * 64 + d] = v;
                else             Vt[((size_t)g * 64 + d) * 1568 + pix] = v;
            }
        }
    }
}

// ---------------------------------------------------------------------------
// Kernel 2: flash attention with decomposed rel-pos bias computed in-block.
// Block: 1 head (g) x 64 queries (4 waves x 16 rows). 49 key-tiles of 32.
__global__ __launch_bounds__(256) void flash_attn(
    const bf16* __restrict__ Qb, const bf16* __restrict__ Kb,
    const bf16* __restrict__ Vt, const float* __restrict__ rph,
    const float* __restrict__ rpw, bf16* __restrict__ AO) {
    const int qblk = blockIdx.x, g = blockIdx.y;
    const int q0 = qblk * 64;
    __shared__ bf16 Qs[64 * 72];        // [q_local][d], padded
    __shared__ float relh_s[64 * 56];   // [q_local][hk]
    __shared__ float relw_s[64 * 28];   // [q_local][wk]
    __shared__ bf16 Ks[32 * 72];        // [key][d], padded
    __shared__ bf16 Vts[64 * 40];       // [d][key], padded
    __shared__ bf16 Ps[4 * 16 * 40];    // per-wave P, padded rows

    const int t = threadIdx.x, wid = t >> 6, lane = t & 63;
    const int lm = lane & 15, quad = lane >> 4;

    // stage Q tile [64][64] -> LDS (rows clamped for the q tail)
    for (int c = t; c < 512; c += 256) {
        const int row = c >> 3, col = (c & 7) * 8;
        const int qg = min(q0 + row, 1567);
        *(bf16x8*)&Qs[row * 72 + col] =
            *(const bf16x8*)&Qb[((size_t)g * 1568 + qg) * 64 + col];
    }
    __syncthreads();

    // rel-pos biases: relh_s[ql][hk] = Q[ql].rph[hq-hk+55]; relw_s similar.
    for (int e = t; e < 64 * 84; e += 256) {
        const int ql = e / 84, j = e - ql * 84;
        const int qg = min(q0 + ql, 1567);
        const int hq = qg / 28, wq = qg - hq * 28;
        const float* rp;
        float* dst;
        if (j < 56) { rp = rph + (hq - j + 55) * 64;        dst = &relh_s[ql * 56 + j]; }
        else { const int wk = j - 56;
               rp = rpw + (wq - wk + 27) * 64;              dst = &relw_s[ql * 28 + wk]; }
        float s = 0.f;
#pragma unroll
        for (int c = 0; c < 8; c++) {
            const bf16x8 qv = *(const bf16x8*)&Qs[ql * 72 + c * 8];
            const f32x4 r0 = *(const f32x4*)&rp[c * 8];
            const f32x4 r1 = *(const f32x4*)&rp[c * 8 + 4];
#pragma unroll
            for (int k = 0; k < 4; k++) s += b2f(qv[k]) * r0[k];
#pragma unroll
            for (int k = 0; k < 4; k++) s += b2f(qv[k + 4]) * r1[k];
        }
        *dst = s;
    }

    // Q MFMA A-fragments from LDS
    const int qrow_l = wid * 16 + lm;
    const bf16x8 qf0 = *(const bf16x8*)&Qs[qrow_l * 72 + quad * 8];
    const bf16x8 qf1 = *(const bf16x8*)&Qs[qrow_l * 72 + 32 + quad * 8];

    f32x4 o[4] = {};
    float m_r[4], l_r[4];
    for (int r = 0; r < 4; r++) { m_r[r] = -1e30f; l_r[r] = 0.f; }
    const float scale = 0.125f;

    const int ks_k = t >> 3, ks_d = (t & 7) * 8;   // K staging coords
    const int vs_d = t >> 2, vs_k = (t & 3) * 8;   // Vt staging coords

    for (int kt = 0; kt < 49; kt++) {
        const int kb = kt * 32;
        __syncthreads();
        *(bf16x8*)&Ks[ks_k * 72 + ks_d] =
            *(const bf16x8*)&Kb[((size_t)g * 1568 + kb + ks_k) * 64 + ks_d];
        *(bf16x8*)&Vts[vs_d * 40 + vs_k] =
            *(const bf16x8*)&Vt[((size_t)g * 64 + vs_d) * 1568 + kb + vs_k];
        __syncthreads();

        // S = Q K^T  (two 16-key fragments)
        f32x4 s0 = {}, s1 = {};
        {
            const bf16x8 ka0 = *(const bf16x8*)&Ks[lm * 72 + quad * 8];
            const bf16x8 ka1 = *(const bf16x8*)&Ks[lm * 72 + 32 + quad * 8];
            s0 = __builtin_amdgcn_mfma_f32_16x16x32_bf16(qf0, ka0, s0, 0, 0, 0);
            s0 = __builtin_amdgcn_mfma_f32_16x16x32_bf16(qf1, ka1, s0, 0, 0, 0);
            const bf16x8 kb0 = *(const bf16x8*)&Ks[(16 + lm) * 72 + quad * 8];
            const bf16x8 kb1 = *(const bf16x8*)&Ks[(16 + lm) * 72 + 32 + quad * 8];
            s1 = __builtin_amdgcn_mfma_f32_16x16x32_bf16(qf0, kb0, s1, 0, 0, 0);
            s1 = __builtin_amdgcn_mfma_f32_16x16x32_bf16(qf1, kb1, s1, 0, 0, 0);
        }

        // scale + rel-pos bias
        const int key0 = kb + lm, key1 = key0 + 16;
        const int hk0 = key0 / 28, wk0 = key0 - hk0 * 28;
        const int hk1 = key1 / 28, wk1 = key1 - hk1 * 28;
        const int qbase_l = wid * 16 + quad * 4;
        float sv0[4], sv1[4];
        for (int r = 0; r < 4; r++) {
            const int ql = qbase_l + r;
            sv0[r] = s0[r] * scale + relh_s[ql * 56 + hk0] + relw_s[ql * 28 + wk0];
            sv1[r] = s1[r] * scale + relh_s[ql * 56 + hk1] + relw_s[ql * 28 + wk1];
        }

        // online softmax (rows live in 16-lane groups; butterfly over 16 cols)
        float alpha[4], p0[4], p1[4];
        for (int r = 0; r < 4; r++) {
            float v = fmaxf(sv0[r], sv1[r]);
            for (int off = 1; off < 16; off <<= 1) v = fmaxf(v, __shfl_xor(v, off, 64));
            const float mn = fmaxf(m_r[r], v);
            alpha[r] = __expf(m_r[r] - mn);
            m_r[r] = mn;
            p0[r] = __expf(sv0[r] - mn);
            p1[r] = __expf(sv1[r] - mn);
            float ss = p0[r] + p1[r];
            for (int off = 1; off < 16; off <<= 1) ss += __shfl_xor(ss, off, 64);
            l_r[r] = l_r[r] * alpha[r] + ss;
        }
        for (int dt = 0; dt < 4; dt++)
            for (int r = 0; r < 4; r++) o[dt][r] *= alpha[r];

        // P -> LDS (A-operand layout), wave-local round trip
        bf16* Pw = &Ps[wid * 640];
        for (int r = 0; r < 4; r++) {
            Pw[(quad * 4 + r) * 40 + lm]      = (bf16)p0[r];
            Pw[(quad * 4 + r) * 40 + 16 + lm] = (bf16)p1[r];
        }
        __asm__ volatile("s_waitcnt lgkmcnt(0)" ::: "memory");
        const bf16x8 pf = *(const bf16x8*)&Pw[lm * 40 + quad * 8];
        for (int dt = 0; dt < 4; dt++) {
            const bf16x8 vf = *(const bf16x8*)&Vts[(dt * 16 + lm) * 40 + quad * 8];
            o[dt] = __builtin_amdgcn_mfma_f32_16x16x32_bf16(pf, vf, o[dt], 0, 0, 0);
        }
    }

    // epilogue: AO[b][pix][h*64+d] bf16
    const int qrow0 = q0 + wid * 16 + quad * 4;
    if (q0 + wid * 16 < 1568) {
        const int bo = g >> 4, h = g & 15;
        for (int r = 0; r < 4; r++) {
            const float inv = 1.0f / l_r[r];
            const size_t base = ((size_t)bo * 1568 + qrow0 + r) * 1024 + h * 64;
            for (int dt = 0; dt < 4; dt++)
                AO[base + dt * 16 + lm] = (bf16)(o[dt][r] * inv);
        }
    }
}

// ---------------------------------------------------------------------------
// Kernel 3: output projection. A=[6272,1024] AO bf16 (ws), W=[1024,1024] fp32.
// A staged via width-16 global_load_lds; W converted fp32->bf16 at stage time.
// Output fp32.
__global__ __launch_bounds__(256) void proj_gemm(
    const bf16* __restrict__ A, const float* __restrict__ W,
    const float* __restrict__ bias, float* __restrict__ out) {
    __shared__ bf16 As[128 * 32];
    __shared__ bf16 Bs[128 * 32];
    const int t = threadIdx.x;
    const int wid = t >> 6, lane = t & 63;
    const int m0 = blockIdx.x * 128, n0 = blockIdx.y * 128;
    const int wm = (wid & 1) * 64, wn = (wid >> 1) * 64;
    const int r_i = lane >> 2;        // row within a 16-row staging block
    const int c8 = (lane & 3) * 8;    // k-column (8 bf16 = 16B)
    const int lm = lane & 15, quad = lane >> 4;

    f32x4 acc[4][4] = {};
    for (int k0 = 0; k0 < 1024; k0 += 32) {
        __syncthreads();
        for (int i = 0; i < 2; i++) {
            const int blk = wid * 2 + i;
            async_cp16(A + (size_t)(m0 + blk * 16 + r_i) * 1024 + k0 + c8, As + blk * 512);
        }
        for (int i = 0; i < 4; i++) {
            const int idx = t + i * 256;
            const int row = idx >> 3, c4 = (idx & 7) * 4;
            const f32x4 wv = *(const f32x4*)&W[(size_t)(n0 + row) * 1024 + k0 + c4];
            *(bf16x4*)&Bs[row * 32 + c4] = cvt4(wv);
        }
        __syncthreads();
        bf16x8 af[4], bfr[4];
        for (int x = 0; x < 4; x++) {
            af[x]  = *(const bf16x8*)&As[(wm + x * 16 + lm) * 32 + quad * 8];
            bfr[x] = *(const bf16x8*)&Bs[(wn + x * 16 + lm) * 32 + quad * 8];
        }
        for (int mt = 0; mt < 4; mt++)
            for (int nt = 0; nt < 4; nt++)
                acc[mt][nt] = __builtin_amdgcn_mfma_f32_16x16x32_bf16(af[mt], bfr[nt], acc[mt][nt], 0, 0, 0);
    }
    for (int nt = 0; nt < 4; nt++) {
        const int n_ = n0 + wn + nt * 16 + lm;
        const float bv = bias[n_];
        for (int mt = 0; mt < 4; mt++)
            for (int r = 0; r < 4; r++) {
                const int m_ = m0 + wm + mt * 16 + quad * 4 + r;
                out[(size_t)m_ * 1024 + n_] = acc[mt][nt][r] + bv;
            }
    }
}

// ---------------------------------------------------------------------------
extern "C" void kernel_launch(void* const* d_in, const int* in_sizes, int n_in,
                              void* d_out, int out_size, void* d_ws, size_t ws_size,
                              hipStream_t stream) {
    const float* hs     = (const float*)d_in[0];
    const float* qkv_w  = (const float*)d_in[1];
    const float* qkv_b  = (const float*)d_in[2];
    const float* proj_w = (const float*)d_in[3];
    const float* proj_b = (const float*)d_in[4];
    const float* rph    = (const float*)d_in[5];
    const float* rpw    = (const float*)d_in[6];
    float* out = (float*)d_out;

    const size_t GQ = (size_t)64 * 1568 * 64;  // 6,422,528 elems per Q/K/V
    bf16* Qb = (bf16*)d_ws;                    // [g][pix][64]
    bf16* Kb = Qb + GQ;                        // [g][pix][64]
    bf16* Vt = Kb + GQ;                        // [g][d][pix] (transposed V)
    bf16* AO = Vt + GQ;                        // [6272][1024]
    // total workspace: 4 * GQ * 2 B = 51.4 MB

    qkv_gemm<<<dim3(49, 24), 256, 0, stream>>>(hs, qkv_w, qkv_b, Qb, Kb, Vt);
    flash_attn<<<dim3(25, 64), 256, 0, stream>>>(Qb, Kb, Vt, rph, rpw, AO);
    proj_gemm<<<dim3(49, 8), 256, 0, stream>>>(AO, proj_w, proj_b, out);
}

// Round 4
// 626.868 us; speedup vs baseline: 1.0562x; 1.0562x over previous
//
#include <hip/hip_runtime.h>
#include <hip/hip_bf16.h>
#include <stdint.h>

typedef __bf16 bf16;
typedef __bf16 bf16x2 __attribute__((ext_vector_type(2)));
typedef __bf16 bf16x4 __attribute__((ext_vector_type(4)));
typedef __bf16 bf16x8 __attribute__((ext_vector_type(8)));
typedef float f32x4 __attribute__((ext_vector_type(4)));

#define AS1 __attribute__((address_space(1)))
#define AS3 __attribute__((address_space(3)))

static __device__ __forceinline__ float b2f(bf16 x) { return (float)x; }

static __device__ __forceinline__ void async_cp16(const bf16* g, bf16* l) {
    __builtin_amdgcn_global_load_lds((const AS1 void*)g, (AS3 void*)l, 16, 0, 0);
}

static __device__ __forceinline__ bf16x4 cvt4(f32x4 v) {
    bf16x4 r;
    r[0] = (bf16)v[0]; r[1] = (bf16)v[1]; r[2] = (bf16)v[2]; r[3] = (bf16)v[3];
    return r;
}

// ---------------------------------------------------------------------------
// Kernel 1: QKV projection. A=[6272,1024] hs fp32, W=[3072,1024] fp32 (B^T).
// fp32 tiles converted to bf16 at LDS-stage time (m97-style hot loop).
// Q,K -> [g][pix][64]; V -> [g][d][ppix] with within-32-tile key permutation
// ppix = base32 | ((lk&15)<<1) | (lk>>4)  so flash's P/V share the same
// permuted key order (PV MFMA sums over any consistent permutation).
__global__ __launch_bounds__(256) void qkv_gemm(
    const float* __restrict__ A, const float* __restrict__ W,
    const float* __restrict__ bias, bf16* __restrict__ Qb,
    bf16* __restrict__ Kb, bf16* __restrict__ Vt) {
    __shared__ bf16 As[128 * 32];
    __shared__ bf16 Bs[128 * 32];
    const int t = threadIdx.x;
    const int wid = t >> 6, lane = t & 63;
    const int m0 = blockIdx.x * 128, n0 = blockIdx.y * 128;
    const int wm = (wid & 1) * 64, wn = (wid >> 1) * 64;
    const int lm = lane & 15, quad = lane >> 4;

    f32x4 acc[4][4] = {};
    for (int k0 = 0; k0 < 1024; k0 += 32) {
        __syncthreads();
        for (int i = 0; i < 4; i++) {
            const int idx = t + i * 256;            // 0..1023
            const int row = idx >> 3, c4 = (idx & 7) * 4;
            const f32x4 av = *(const f32x4*)&A[(size_t)(m0 + row) * 1024 + k0 + c4];
            const f32x4 wv = *(const f32x4*)&W[(size_t)(n0 + row) * 1024 + k0 + c4];
            *(bf16x4*)&As[row * 32 + c4] = cvt4(av);
            *(bf16x4*)&Bs[row * 32 + c4] = cvt4(wv);
        }
        __syncthreads();
        bf16x8 af[4], bfr[4];
        for (int x = 0; x < 4; x++) {
            af[x]  = *(const bf16x8*)&As[(wm + x * 16 + lm) * 32 + quad * 8];
            bfr[x] = *(const bf16x8*)&Bs[(wn + x * 16 + lm) * 32 + quad * 8];
        }
        for (int mt = 0; mt < 4; mt++)
            for (int nt = 0; nt < 4; nt++)
                acc[mt][nt] = __builtin_amdgcn_mfma_f32_16x16x32_bf16(af[mt], bfr[nt], acc[mt][nt], 0, 0, 0);
    }
    // epilogue: n = s*1024 + h*64 + d; m = b*1568 + pix
    for (int nt = 0; nt < 4; nt++) {
        const int n_ = n0 + wn + nt * 16 + lm;
        const float bv = bias[n_];
        const int s = n_ >> 10, rem = n_ & 1023;
        const int h = rem >> 6, d = rem & 63;
        for (int mt = 0; mt < 4; mt++) {
            for (int r = 0; r < 4; r++) {
                const int m_ = m0 + wm + mt * 16 + quad * 4 + r;
                const int b = m_ / 1568;
                const int pix = m_ - b * 1568;
                const int g = b * 16 + h;
                const bf16 v = (bf16)(acc[mt][nt][r] + bv);
                if (s == 0)      Qb[((size_t)g * 1568 + pix) * 64 + d] = v;
                else if (s == 1) Kb[((size_t)g * 1568 + pix) * 64 + d] = v;
                else {
                    const int lk = pix & 31;
                    const int ppix = (pix & ~31) | ((lk & 15) << 1) | (lk >> 4);
                    Vt[((size_t)g * 64 + d) * 1568 + ppix] = v;
                }
            }
        }
    }
}

// ---------------------------------------------------------------------------
// Kernel 2: flash attention, fixed-shift softmax (no running max — logits are
// bounded ~|Q||K|/8 + bias << 98, so exp(logit-10) cannot overflow and the
// final 1/l normalization cancels the shift exactly).
// Block: 1 head (g) x 64 queries (4 waves x 16 rows). 49 key-tiles of 32.
__global__ __launch_bounds__(256) void flash_attn(
    const bf16* __restrict__ Qb, const bf16* __restrict__ Kb,
    const bf16* __restrict__ Vt, const float* __restrict__ rph,
    const float* __restrict__ rpw, bf16* __restrict__ AO) {
    const int qblk = blockIdx.x, g = blockIdx.y;
    const int q0 = qblk * 64;
    // 40448 B total -> 4 blocks/CU. Ps aliases Qs (Qs dead after prologue;
    // first Ps write is after the loop's barriers, all Qs reads are before).
    __shared__ __align__(16) char smem[40448];
    bf16*  Qs     = (bf16*)smem;            // [64][72] prologue only
    bf16*  Ps     = (bf16*)smem;            // [4][16][40] aliases Qs
    float* relh_s = (float*)(smem + 9216);  // [64][56]
    float* relw_s = (float*)(smem + 23552); // [64][28]
    bf16*  Ks     = (bf16*)(smem + 30720);  // [32][72]
    bf16*  Vts    = (bf16*)(smem + 35328);  // [64][40] (cols = permuted pos)

    const int t = threadIdx.x, wid = t >> 6, lane = t & 63;
    const int lm = lane & 15, quad = lane >> 4;

    // stage Q tile [64][64] -> LDS (rows clamped for the q tail)
    for (int c = t; c < 512; c += 256) {
        const int row = c >> 3, col = (c & 7) * 8;
        const int qg = min(q0 + row, 1567);
        *(bf16x8*)&Qs[row * 72 + col] =
            *(const bf16x8*)&Qb[((size_t)g * 1568 + qg) * 64 + col];
    }
    __syncthreads();

    // rel-pos biases: relh_s[ql][hk] = Q[ql].rph[hq-hk+55]; relw_s similar.
    for (int e = t; e < 64 * 84; e += 256) {
        const int ql = e / 84, j = e - ql * 84;
        const int qg = min(q0 + ql, 1567);
        const int hq = qg / 28, wq = qg - hq * 28;
        const float* rp;
        float* dst;
        if (j < 56) { rp = rph + (hq - j + 55) * 64;        dst = &relh_s[ql * 56 + j]; }
        else { const int wk = j - 56;
               rp = rpw + (wq - wk + 27) * 64;              dst = &relw_s[ql * 28 + wk]; }
        float s = 0.f;
#pragma unroll
        for (int c = 0; c < 8; c++) {
            const bf16x8 qv = *(const bf16x8*)&Qs[ql * 72 + c * 8];
            const f32x4 r0 = *(const f32x4*)&rp[c * 8];
            const f32x4 r1 = *(const f32x4*)&rp[c * 8 + 4];
#pragma unroll
            for (int k = 0; k < 4; k++) s += b2f(qv[k]) * r0[k];
#pragma unroll
            for (int k = 0; k < 4; k++) s += b2f(qv[k + 4]) * r1[k];
        }
        *dst = s;
    }

    // Q MFMA A-fragments from LDS (before first loop barrier — Qs dies here)
    const int qrow_l = wid * 16 + lm;
    const bf16x8 qf0 = *(const bf16x8*)&Qs[qrow_l * 72 + quad * 8];
    const bf16x8 qf1 = *(const bf16x8*)&Qs[qrow_l * 72 + 32 + quad * 8];

    f32x4 o[4] = {};
    float l_lane[4] = {0.f, 0.f, 0.f, 0.f};
    const float scale = 0.125f;
    const float SHIFT = 10.0f;

    const int ks_k = t >> 3, ks_d = (t & 7) * 8;   // K staging coords
    const int vs_d = t >> 2, vs_k = (t & 3) * 8;   // Vt staging coords
    bf16* Pw = &Ps[wid * 640];
    const int qbase_l = wid * 16 + quad * 4;

    for (int kt = 0; kt < 49; kt++) {
        const int kb = kt * 32;
        __syncthreads();
        *(bf16x8*)&Ks[ks_k * 72 + ks_d] =
            *(const bf16x8*)&Kb[((size_t)g * 1568 + kb + ks_k) * 64 + ks_d];
        *(bf16x8*)&Vts[vs_d * 40 + vs_k] =
            *(const bf16x8*)&Vt[((size_t)g * 64 + vs_d) * 1568 + kb + vs_k];
        __syncthreads();

        // S = Q K^T  (two 16-key fragments; key = kb + lm / kb + 16 + lm)
        f32x4 s0 = {}, s1 = {};
        {
            const bf16x8 ka0 = *(const bf16x8*)&Ks[lm * 72 + quad * 8];
            const bf16x8 ka1 = *(const bf16x8*)&Ks[lm * 72 + 32 + quad * 8];
            s0 = __builtin_amdgcn_mfma_f32_16x16x32_bf16(qf0, ka0, s0, 0, 0, 0);
            s0 = __builtin_amdgcn_mfma_f32_16x16x32_bf16(qf1, ka1, s0, 0, 0, 0);
            const bf16x8 kb0 = *(const bf16x8*)&Ks[(16 + lm) * 72 + quad * 8];
            const bf16x8 kb1 = *(const bf16x8*)&Ks[(16 + lm) * 72 + 32 + quad * 8];
            s1 = __builtin_amdgcn_mfma_f32_16x16x32_bf16(qf0, kb0, s1, 0, 0, 0);
            s1 = __builtin_amdgcn_mfma_f32_16x16x32_bf16(qf1, kb1, s1, 0, 0, 0);
        }

        // bias + fixed-shift exp; P packed as bf16x2 at permuted positions
        const int key0 = kb + lm, key1 = key0 + 16;
        const int hk0 = key0 / 28, wk0 = key0 - hk0 * 28;
        const int hk1 = key1 / 28, wk1 = key1 - hk1 * 28;
        for (int r = 0; r < 4; r++) {
            const int ql = qbase_l + r;
            const float p0 = __expf(s0[r] * scale + relh_s[ql * 56 + hk0]
                                    + relw_s[ql * 28 + wk0] - SHIFT);
            const float p1 = __expf(s1[r] * scale + relh_s[ql * 56 + hk1]
                                    + relw_s[ql * 28 + wk1] - SHIFT);
            l_lane[r] += p0 + p1;
            bf16x2 pp; pp[0] = (bf16)p0; pp[1] = (bf16)p1;
            *(bf16x2*)&Pw[(quad * 4 + r) * 40 + lm * 2] = pp;  // pos 2lm, 2lm+1
        }
        __asm__ volatile("s_waitcnt lgkmcnt(0)" ::: "memory");
        const bf16x8 pf = *(const bf16x8*)&Pw[lm * 40 + quad * 8];
        for (int dt = 0; dt < 4; dt++) {
            const bf16x8 vf = *(const bf16x8*)&Vts[(dt * 16 + lm) * 40 + quad * 8];
            o[dt] = __builtin_amdgcn_mfma_f32_16x16x32_bf16(pf, vf, o[dt], 0, 0, 0);
        }
    }

    // single l reduction (16 lanes per row group), then epilogue
    const int qrow0 = q0 + wid * 16 + quad * 4;
    if (q0 + wid * 16 < 1568) {
        const int bo = g >> 4, h = g & 15;
        for (int r = 0; r < 4; r++) {
            float ll = l_lane[r];
            for (int off = 1; off < 16; off <<= 1) ll += __shfl_xor(ll, off, 64);
            const float inv = 1.0f / ll;
            const size_t base = ((size_t)bo * 1568 + qrow0 + r) * 1024 + h * 64;
            for (int dt = 0; dt < 4; dt++)
                AO[base + dt * 16 + lm] = (bf16)(o[dt][r] * inv);
        }
    }
}

// ---------------------------------------------------------------------------
// Kernel 3: output projection. A=[6272,1024] AO bf16 (ws), W=[1024,1024] fp32.
__global__ __launch_bounds__(256) void proj_gemm(
    const bf16* __restrict__ A, const float* __restrict__ W,
    const float* __restrict__ bias, float* __restrict__ out) {
    __shared__ bf16 As[128 * 32];
    __shared__ bf16 Bs[128 * 32];
    const int t = threadIdx.x;
    const int wid = t >> 6, lane = t & 63;
    const int m0 = blockIdx.x * 128, n0 = blockIdx.y * 128;
    const int wm = (wid & 1) * 64, wn = (wid >> 1) * 64;
    const int r_i = lane >> 2;
    const int c8 = (lane & 3) * 8;
    const int lm = lane & 15, quad = lane >> 4;

    f32x4 acc[4][4] = {};
    for (int k0 = 0; k0 < 1024; k0 += 32) {
        __syncthreads();
        for (int i = 0; i < 2; i++) {
            const int blk = wid * 2 + i;
            async_cp16(A + (size_t)(m0 + blk * 16 + r_i) * 1024 + k0 + c8, As + blk * 512);
        }
        for (int i = 0; i < 4; i++) {
            const int idx = t + i * 256;
            const int row = idx >> 3, c4 = (idx & 7) * 4;
            const f32x4 wv = *(const f32x4*)&W[(size_t)(n0 + row) * 1024 + k0 + c4];
            *(bf16x4*)&Bs[row * 32 + c4] = cvt4(wv);
        }
        __syncthreads();
        bf16x8 af[4], bfr[4];
        for (int x = 0; x < 4; x++) {
            af[x]  = *(const bf16x8*)&As[(wm + x * 16 + lm) * 32 + quad * 8];
            bfr[x] = *(const bf16x8*)&Bs[(wn + x * 16 + lm) * 32 + quad * 8];
        }
        for (int mt = 0; mt < 4; mt++)
            for (int nt = 0; nt < 4; nt++)
                acc[mt][nt] = __builtin_amdgcn_mfma_f32_16x16x32_bf16(af[mt], bfr[nt], acc[mt][nt], 0, 0, 0);
    }
    for (int nt = 0; nt < 4; nt++) {
        const int n_ = n0 + wn + nt * 16 + lm;
        const float bv = bias[n_];
        for (int mt = 0; mt < 4; mt++)
            for (int r = 0; r < 4; r++) {
                const int m_ = m0 + wm + mt * 16 + quad * 4 + r;
                out[(size_t)m_ * 1024 + n_] = acc[mt][nt][r] + bv;
            }
    }
}

// ---------------------------------------------------------------------------
extern "C" void kernel_launch(void* const* d_in, const int* in_sizes, int n_in,
                              void* d_out, int out_size, void* d_ws, size_t ws_size,
                              hipStream_t stream) {
    const float* hs     = (const float*)d_in[0];
    const float* qkv_w  = (const float*)d_in[1];
    const float* qkv_b  = (const float*)d_in[2];
    const float* proj_w = (const float*)d_in[3];
    const float* proj_b = (const float*)d_in[4];
    const float* rph    = (const float*)d_in[5];
    const float* rpw    = (const float*)d_in[6];
    float* out = (float*)d_out;

    const size_t GQ = (size_t)64 * 1568 * 64;  // elems per Q/K/V
    bf16* Qb = (bf16*)d_ws;                    // [g][pix][64]
    bf16* Kb = Qb + GQ;                        // [g][pix][64]
    bf16* Vt = Kb + GQ;                        // [g][d][ppix] (permuted keys)
    bf16* AO = Vt + GQ;                        // [6272][1024]
    // total workspace: 4 * GQ * 2 B = 51.4 MB

    qkv_gemm<<<dim3(49, 24), 256, 0, stream>>>(hs, qkv_w, qkv_b, Qb, Kb, Vt);
    flash_attn<<<dim3(25, 64), 256, 0, stream>>>(Qb, Kb, Vt, rph, rpw, AO);
    proj_gemm<<<dim3(49, 8), 256, 0, stream>>>(AO, proj_w, proj_b, out);
}